// Round 9
// baseline (223.060 us; speedup 1.0000x reference)
//
#include <hip/hip_runtime.h>

#define NJ   17
#define FD   128
#define NC   128
#define NNZ  49
#define FPT  16                 // frames per tile (= MFMA M)
#define XROW (NJ*FD)            // 2176 floats per frame
#define TPB  2                  // tiles per block
#define BUFB 20736              // phase buffer stride (bytes), sized for half1
#define WS_WT 65536             // ws offset of wt[128][64] bf16

typedef __attribute__((ext_vector_type(8))) short bf16x8;
typedef __attribute__((ext_vector_type(4))) float f32x4;

__device__ __forceinline__ ushort f2bf(float f) {   // f32 -> bf16 RNE
  unsigned u = __float_as_uint(f);
  u = (u + 0x7fffu + ((u >> 16) & 1u)) >> 16;
  return (ushort)u;
}
__device__ __forceinline__ float bf2f(ushort s) {
  return __uint_as_float(((unsigned)s) << 16);
}
__device__ __forceinline__ unsigned cvtpk(float a, float b) {
  unsigned r;
  asm("v_cvt_pk_bf16_f32 %0, %1, %2" : "=v"(r) : "v"(a), "v"(b));
  return r;
}
__device__ __forceinline__ bf16x8 pack8(f32x4 a, f32x4 b) {
  union { unsigned u[4]; bf16x8 v; } r;
  r.u[0] = cvtpk(a[0], a[1]); r.u[1] = cvtpk(a[2], a[3]);
  r.u[2] = cvtpk(b[0], b[1]); r.u[3] = cvtpk(b[2], b[3]);
  return r.v;
}
__device__ __forceinline__ void axpy(f32x4& o, float s, f32x4 h) {
  o[0] += s * h[0]; o[1] += s * h[1]; o[2] += s * h[2]; o[3] += s * h[3];
}

// counted-vmcnt wait (loads stay in flight across barriers) + sched pin
#define WVM(N) do { asm volatile("s_waitcnt vmcnt(" #N ")" ::: "memory"); \
                    __builtin_amdgcn_sched_barrier(0); } while (0)
// LDS-only barrier: drains ds ops, leaves vmcnt (loads/stores) in flight
#define BARR() do { asm volatile("s_waitcnt lgkmcnt(0)" ::: "memory"); \
                    __builtin_amdgcn_s_barrier(); \
                    __builtin_amdgcn_sched_barrier(0); } while (0)

// ---------------------------------------------------------------------------
// Compile-time Human3.6M skeleton tables (validated end-to-end in r6/r7).
// ---------------------------------------------------------------------------
struct CI { int col, dk, n, jl[3], kk[3]; };
constexpr CI TAB0[9] = {          // half 0: out joints 0..7, cols 0..8
  {0,  0, 3, {1,4,7}, {4,12,20}},
  {1,  5, 2, {0,2,0}, {1,7,0}},
  {2,  8, 2, {1,3,0}, {6,10,0}},
  {3, 11, 1, {2,0,0}, {9,0,0}},
  {4, 13, 2, {0,5,0}, {2,15,0}},
  {5, 16, 2, {4,6,0}, {14,18,0}},
  {6, 19, 1, {5,0,0}, {17,0,0}},
  {7, 21, 1, {0,0,0}, {3,0,0}},
  {8, -1, 1, {7,0,0}, {22,0,0}},
};
constexpr CI TAB1[10] = {         // half 1: out joints 8..16 (local j-8), cols 7..16
  {7, -1, 1, {0,0,0}, {23,0,0}},
  {8, 24, 3, {1,3,6}, {28,33,41}},
  {9, 29, 2, {0,2,0}, {25,31,0}},
  {10,32, 1, {1,0,0}, {30,0,0}},
  {11,34, 2, {0,4,0}, {26,36,0}},
  {12,37, 2, {3,5,0}, {35,39,0}},
  {13,40, 1, {4,0,0}, {38,0,0}},
  {14,42, 2, {0,7,0}, {27,44,0}},
  {15,45, 2, {6,8,0}, {43,47,0}},
  {16,48, 1, {7,0,0}, {46,0,0}},
};
constexpr int RP[NJ + 1] = {0,4,7,10,12,15,18,20,23,28,31,33,36,39,41,44,47,49};

// ---------------------------------------------------------------------------
// Prep (17 blocks x 256) — unchanged (validated r6/r7/r8).
// ---------------------------------------------------------------------------
__global__ void prep_pack_kernel(const float* __restrict__ W,
                                 const float* __restrict__ e,
                                 bf16x8* __restrict__ Wpack,
                                 ushort* __restrict__ wt) {
  const int tid = threadIdx.x;
  if (blockIdx.x < 16) {
    const int idx = blockIdx.x * 256 + tid, n = idx >> 4, kb = idx & 15;
    const float* Wp = W + (size_t)(n >> 7) * (FD * NC) + (n & 127);
    bf16x8 v;
#pragma unroll
    for (int q = 0; q < 8; ++q) v[q] = (short)f2bf(Wp[(size_t)(kb * 8 + q) * NC]);
    Wpack[idx] = v;
  } else if (tid < NC) {
    const int c = tid;
    for (int j = 0; j < NJ; ++j) {
      const int k0 = RP[j], k1 = RP[j + 1];
      float m = -1e30f;
      for (int k = k0; k < k1; ++k) m = fmaxf(m, e[c * NNZ + k]);
      float s = 0.f;
      for (int k = k0; k < k1; ++k) s += expf(e[c * NNZ + k] - m);
      const float inv = 1.f / s;
      for (int k = k0; k < k1; ++k) wt[c * 64 + k] = f2bf(expf(e[c * NNZ + k] - m) * inv);
    }
    for (int k = NNZ; k < 64; ++k) wt[c * 64 + k] = 0;
  }
}

// ---------------------------------------------------------------------------
// One k-quarter compute phase (P constexpr: buffer parity & bfr k-slice static).
// ---------------------------------------------------------------------------
template <int HALF, int P, int JN>
__device__ __forceinline__ void cphase(const char* bb, int foff, int l4,
                                       const bf16x8 (&bfr)[2][4],
                                       const bf16x8 (&wtp)[7],
                                       f32x4 (&oa)[JN]) {
  constexpr int KQ   = P & 3;
  constexpr int COL0 = HALF ? 7 : 0;
  constexpr int NCOL = HALF ? 10 : 9;
  constexpr int JB   = HALF ? 8 : 0;
  const CI* TT = HALF ? TAB1 : TAB0;
  const char* fb = bb + foff;
#pragma unroll
  for (int ci = 0; ci < NCOL; ++ci) {
    const int lc = TT[ci].col - COL0, dk = TT[ci].dk, nn = TT[ci].n;
    const f32x4 lo = *(const f32x4*)(fb + lc * 128 + l4 * 32);
    const f32x4 hi = *(const f32x4*)(fb + lc * 128 + l4 * 32 + 16);
    const bf16x8 af = pack8(lo, hi);
    const f32x4 z = (f32x4){0.f, 0.f, 0.f, 0.f};
    const f32x4 h1 = __builtin_amdgcn_mfma_f32_16x16x32_bf16(af, bfr[1][KQ], z, 0, 0, 0);
    if (dk >= 0) {
      const f32x4 h0 = __builtin_amdgcn_mfma_f32_16x16x32_bf16(af, bfr[0][KQ], z, 0, 0, 0);
      axpy(oa[TT[ci].col - JB], bf2f((ushort)wtp[dk >> 3][dk & 7]), h0);
    }
#pragma unroll
    for (int o = 0; o < 3; ++o)
      if (o < nn)
        axpy(oa[TT[ci].jl[o]], bf2f((ushort)wtp[TT[ci].kk[o] >> 3][TT[ci].kk[o] & 7]), h1);
  }
}

// ---------------------------------------------------------------------------
// Per-half driver: 8 phases (2 tiles x 4 k-quarters), global_load_lds staging
// (zero VGPR), double-buffered LDS, counted vmcnt waits, lgkm-only barriers.
// ---------------------------------------------------------------------------
template <int HALF>
__device__ __forceinline__ void run(const float* __restrict__ x,
                                    const bf16x8* __restrict__ Wpack,
                                    const ushort* __restrict__ wt,
                                    float* __restrict__ out,
                                    char* xs, int slot, int tid) {
  constexpr int COL0 = HALF ? 7 : 0;
  constexpr int JN   = HALF ? 9 : 8;
  constexpr int JB   = HALF ? 8 : 0;
  const int w = tid >> 6, lane = tid & 63, l15 = lane & 15, l4 = lane >> 4;
  const int c = w * 16 + l15;

  // persistent B frags (32 VGPR) + softmax weights (7 VGPR)
  bf16x8 bfr[2][4];
#pragma unroll
  for (int sel = 0; sel < 2; ++sel)
#pragma unroll
    for (int ks = 0; ks < 4; ++ks)
      bfr[sel][ks] = Wpack[(sel * 128 + c) * 16 + ks * 4 + l4];
  bf16x8 wtp[7];
#pragma unroll
  for (int r = 0; r < 7; ++r)
    wtp[r] = *(const bf16x8*)(wt + c * 64 + r * 8);

  f32x4 oa[JN];
#pragma unroll
  for (int j = 0; j < JN; ++j) oa[j] = (f32x4){0.f, 0.f, 0.f, 0.f};

  // read-side LDS frame base (padded layouts)
  const int foff = HALF ? l15 * 1296 : (l15 >> 1) * 2320 + (l15 & 1) * 1152;

  // stage phase p into buf[p&1] via global_load_lds (wave stages frames 2w,2w+1)
  auto issue = [&](int p) {
    const int t = p >> 2, kq = p & 3;
    char* dst = xs + (p & 1) * BUFB;
    const float* gf0 = x + ((size_t)(slot * TPB + t) * FPT + 2 * w) * XROW +
                       COL0 * FD + kq * 32;
    const float* gf1 = gf0 + XROW;
    if (HALF) {
      // frame layout: [col][32 f32] = 1280 B data + 16 B pad, stride 1296
      char* d0 = dst + (2 * w) * 1296;
      __builtin_amdgcn_global_load_lds(gf0 + (lane >> 3) * FD + (lane & 7) * 4,
                                       (void*)d0, 16, 0, 0);
      __builtin_amdgcn_global_load_lds(gf0 + (8 + (lane >> 5)) * FD + (lane & 31),
                                       (void*)(d0 + 1024), 4, 0, 0);
      __builtin_amdgcn_global_load_lds(gf1 + (lane >> 3) * FD + (lane & 7) * 4,
                                       (void*)(d0 + 1296), 16, 0, 0);
      __builtin_amdgcn_global_load_lds(gf1 + (8 + (lane >> 5)) * FD + (lane & 31),
                                       (void*)(d0 + 1296 + 1024), 4, 0, 0);
    } else {
      // frame-pair layout: 2 x 1152 B data + 16 B pad, pair stride 2320
      char* pb = dst + w * 2320;
      const float* s2 = (lane < 8)
          ? gf0 + 8 * FD + lane * 4
          : gf1 + ((lane * 16 - 128) >> 7) * FD + (((lane * 16 - 128) & 127) >> 2);
      __builtin_amdgcn_global_load_lds(gf0 + (lane >> 3) * FD + (lane & 7) * 4,
                                       (void*)pb, 16, 0, 0);
      __builtin_amdgcn_global_load_lds(s2, (void*)(pb + 1024), 16, 0, 0);
      __builtin_amdgcn_global_load_lds(gf1 + (7 + (lane >> 5)) * FD + (lane & 31),
                                       (void*)(pb + 2048), 4, 0, 0);
    }
  };

  auto stores = [&](int t) {   // fire-and-forget scalar stores + acc reset
    float* ob = out + (size_t)(slot * TPB + t) * FPT * XROW;
#pragma unroll
    for (int j = 0; j < JN; ++j) {
#pragma unroll
      for (int q = 0; q < 4; ++q)
        ob[(size_t)(l4 * 4 + q) * XROW + (JB + j) * FD + c] = oa[j][q];
      oa[j] = (f32x4){0.f, 0.f, 0.f, 0.f};
    }
  };

  issue(0); issue(1);
  if (HALF) WVM(4); else WVM(3);     // phase-0 loads landed, phase-1 in flight
  BARR();

  char* b0 = xs;
  char* b1 = xs + BUFB;

  cphase<HALF, 0, JN>(b0, foff, l4, bfr, wtp, oa);
  BARR(); issue(2); if (HALF) WVM(4); else WVM(3); BARR();
  cphase<HALF, 1, JN>(b1, foff, l4, bfr, wtp, oa);
  BARR(); issue(3); if (HALF) WVM(4); else WVM(3); BARR();
  cphase<HALF, 2, JN>(b0, foff, l4, bfr, wtp, oa);
  BARR(); issue(4); if (HALF) WVM(4); else WVM(3); BARR();
  cphase<HALF, 3, JN>(b1, foff, l4, bfr, wtp, oa);
  stores(0);                               // 32/36 stores enter vmcnt FIFO here
  BARR(); issue(5); if (HALF) WVM(40); else WVM(35); BARR();
  cphase<HALF, 4, JN>(b0, foff, l4, bfr, wtp, oa);
  BARR(); issue(6); if (HALF) WVM(4); else WVM(3); BARR();
  cphase<HALF, 5, JN>(b1, foff, l4, bfr, wtp, oa);
  BARR(); issue(7); if (HALF) WVM(4); else WVM(3); BARR();
  cphase<HALF, 6, JN>(b0, foff, l4, bfr, wtp, oa);
  BARR(); WVM(0); BARR();
  cphase<HALF, 7, JN>(b1, foff, l4, bfr, wtp, oa);
  stores(1);
}

// ---------------------------------------------------------------------------
__global__ __launch_bounds__(512, 4) void fused_kernel(
    const float*  __restrict__ x,
    const bf16x8* __restrict__ Wpack,
    const ushort* __restrict__ wt,
    float*        __restrict__ out) {
  __shared__ __align__(16) char xs[2 * BUFB];   // 41472 B double buffer
  const int slot = blockIdx.x >> 1;
  if (blockIdx.x & 1) run<1>(x, Wpack, wt, out, xs, slot, threadIdx.x);
  else                run<0>(x, Wpack, wt, out, xs, slot, threadIdx.x);
}

// ---------------------------------------------------------------------------
extern "C" void kernel_launch(void* const* d_in, const int* in_sizes, int n_in,
                              void* d_out, int out_size, void* d_ws, size_t ws_size,
                              hipStream_t stream) {
  const float* x = (const float*)d_in[0];   // [B,T,J,F]
  const float* W = (const float*)d_in[1];   // [2,F,C]
  const float* e = (const float*)d_in[2];   // [C,NNZ]
  float* out = (float*)d_out;

  bf16x8* Wpack = (bf16x8*)d_ws;
  ushort* wt    = (ushort*)((char*)d_ws + WS_WT);

  prep_pack_kernel<<<17, 256, 0, stream>>>(W, e, Wpack, wt);

  const int frames = in_sizes[0] / XROW;    // 15552
  const int slots  = frames / (FPT * TPB);  // 486
  fused_kernel<<<slots * 2, 512, 0, stream>>>(x, Wpack, wt, out);
}

// Round 10
// 144.337 us; speedup vs baseline: 1.5454x; 1.5454x over previous
//
#include <hip/hip_runtime.h>

#define NJ   17
#define FD   128
#define NC   128
#define NNZ  49
#define FPT  16                 // frames per tile (= MFMA M)
#define XROW (NJ*FD)            // 2176 floats per frame
#define TPB  2                  // tiles per block
#define SLOT 16384              // LDS slot bytes (max 4-col window, bf16)
#define WS_WT 65536             // ws offset of wt[128][64] bf16

typedef __attribute__((ext_vector_type(8))) short bf16x8;
typedef __attribute__((ext_vector_type(4))) float f32x4;

__device__ __forceinline__ ushort f2bf(float f) {   // f32 -> bf16 RNE
  unsigned u = __float_as_uint(f);
  u = (u + 0x7fffu + ((u >> 16) & 1u)) >> 16;
  return (ushort)u;
}
__device__ __forceinline__ float bf2f(ushort s) {
  return __uint_as_float(((unsigned)s) << 16);
}
__device__ __forceinline__ unsigned cvtpk(float a, float b) {
  unsigned r;
  asm("v_cvt_pk_bf16_f32 %0, %1, %2" : "=v"(r) : "v"(a), "v"(b));
  return r;
}
__device__ __forceinline__ bf16x8 pack8(float4 a, float4 b) {
  union { unsigned u[4]; bf16x8 v; } r;
  r.u[0] = cvtpk(a.x, a.y); r.u[1] = cvtpk(a.z, a.w);
  r.u[2] = cvtpk(b.x, b.y); r.u[3] = cvtpk(b.z, b.w);
  return r.v;
}
__device__ __forceinline__ void axpy(f32x4& o, float s, f32x4 h) {
  o[0] += s * h[0]; o[1] += s * h[1]; o[2] += s * h[2]; o[3] += s * h[3];
}

// LDS-only barrier: drains ds ops (lgkm), leaves vmem (loads/stores) in flight.
#define BARR() do { asm volatile("s_waitcnt lgkmcnt(0)" ::: "memory"); \
                    __builtin_amdgcn_s_barrier(); \
                    __builtin_amdgcn_sched_barrier(0); } while (0)

// ---------------------------------------------------------------------------
// Compile-time Human3.6M skeleton tables (validated end-to-end r6-r9).
// ---------------------------------------------------------------------------
struct CI { int col, dk, n, jl[3], kk[3]; };
constexpr CI TAB0[9] = {          // half 0: out joints 0..7, cols 0..8
  {0,  0, 3, {1,4,7}, {4,12,20}},
  {1,  5, 2, {0,2,0}, {1,7,0}},
  {2,  8, 2, {1,3,0}, {6,10,0}},
  {3, 11, 1, {2,0,0}, {9,0,0}},
  {4, 13, 2, {0,5,0}, {2,15,0}},
  {5, 16, 2, {4,6,0}, {14,18,0}},
  {6, 19, 1, {5,0,0}, {17,0,0}},
  {7, 21, 1, {0,0,0}, {3,0,0}},
  {8, -1, 1, {7,0,0}, {22,0,0}},
};
constexpr CI TAB1[10] = {         // half 1: out joints 8..16 (local j-8), cols 7..16
  {7, -1, 1, {0,0,0}, {23,0,0}},
  {8, 24, 3, {1,3,6}, {28,33,41}},
  {9, 29, 2, {0,2,0}, {25,31,0}},
  {10,32, 1, {1,0,0}, {30,0,0}},
  {11,34, 2, {0,4,0}, {26,36,0}},
  {12,37, 2, {3,5,0}, {35,39,0}},
  {13,40, 1, {4,0,0}, {38,0,0}},
  {14,42, 2, {0,7,0}, {27,44,0}},
  {15,45, 2, {6,8,0}, {43,47,0}},
  {16,48, 1, {7,0,0}, {46,0,0}},
};
constexpr int RP[NJ + 1] = {0,4,7,10,12,15,18,20,23,28,31,33,36,39,41,44,47,49};

// ---------------------------------------------------------------------------
// Prep (17 blocks x 256) — unchanged (validated r6-r9).
// ---------------------------------------------------------------------------
__global__ void prep_pack_kernel(const float* __restrict__ W,
                                 const float* __restrict__ e,
                                 bf16x8* __restrict__ Wpack,
                                 ushort* __restrict__ wt) {
  const int tid = threadIdx.x;
  if (blockIdx.x < 16) {
    const int idx = blockIdx.x * 256 + tid, n = idx >> 4, kb = idx & 15;
    const float* Wp = W + (size_t)(n >> 7) * (FD * NC) + (n & 127);
    bf16x8 v;
#pragma unroll
    for (int q = 0; q < 8; ++q) v[q] = (short)f2bf(Wp[(size_t)(kb * 8 + q) * NC]);
    Wpack[idx] = v;
  } else if (tid < NC) {
    const int c = tid;
    for (int j = 0; j < NJ; ++j) {
      const int k0 = RP[j], k1 = RP[j + 1];
      float m = -1e30f;
      for (int k = k0; k < k1; ++k) m = fmaxf(m, e[c * NNZ + k]);
      float s = 0.f;
      for (int k = k0; k < k1; ++k) s += expf(e[c * NNZ + k] - m);
      const float inv = 1.f / s;
      for (int k = k0; k < k1; ++k) wt[c * 64 + k] = f2bf(expf(e[c * NNZ + k] - m) * inv);
    }
    for (int k = NNZ; k < 64; ++k) wt[c * 64 + k] = 0;
  }
}

// ---------------------------------------------------------------------------
// Compute one col-window [CI_LO, CI_HI) from LDS slot sb (r7-verbatim math).
// ---------------------------------------------------------------------------
template <int HALF, int CI_LO, int CI_HI, int NW>
__device__ __forceinline__ void cwin(const char* sb, int l15, int l4,
                                     const bf16x8 (&bfr)[2][4],
                                     const bf16x8 (&wtp)[NW],
                                     f32x4* oa) {
  constexpr int JB  = HALF ? 8 : 0;
  constexpr int WB  = HALF ? 2 : 0;
  constexpr int NCS = CI_HI - CI_LO;
  const CI* TT = HALF ? TAB1 : TAB0;
#pragma unroll
  for (int ci = CI_LO; ci < CI_HI; ++ci) {
    const int lc = ci - CI_LO, dk = TT[ci].dk, nn = TT[ci].n;
    bf16x8 af[4];
#pragma unroll
    for (int ks = 0; ks < 4; ++ks) {
      const int byte = l15 * (NCS * 256) + lc * 256 +
                       (((ks * 4 + l4) * 16) ^ ((l15 & 7) << 4));
      af[ks] = *(const bf16x8*)(sb + byte);
    }
    f32x4 h1 = (f32x4){0.f, 0.f, 0.f, 0.f};
#pragma unroll
    for (int ks = 0; ks < 4; ++ks)
      h1 = __builtin_amdgcn_mfma_f32_16x16x32_bf16(af[ks], bfr[1][ks], h1, 0, 0, 0);
    if (dk >= 0) {
      f32x4 h0 = (f32x4){0.f, 0.f, 0.f, 0.f};
#pragma unroll
      for (int ks = 0; ks < 4; ++ks)
        h0 = __builtin_amdgcn_mfma_f32_16x16x32_bf16(af[ks], bfr[0][ks], h0, 0, 0, 0);
      axpy(oa[TT[ci].col - JB], bf2f((ushort)wtp[(dk >> 3) - WB][dk & 7]), h0);
    }
#pragma unroll
    for (int o = 0; o < 3; ++o)
      if (o < nn)
        axpy(oa[TT[ci].jl[o]],
             bf2f((ushort)wtp[(TT[ci].kk[o] >> 3) - WB][TT[ci].kk[o] & 7]), h1);
  }
}

// ---------------------------------------------------------------------------
// Per-half driver: 2 tiles x 3 col-segments, 2-slot LDS ping-pong,
// reg prefetch v[4] (dead into STAGE each iter -> no spill), lgkm barriers.
// ---------------------------------------------------------------------------
template <int HALF>
__device__ __forceinline__ void run(const float* __restrict__ x,
                                    const bf16x8* __restrict__ Wpack,
                                    const ushort* __restrict__ wt,
                                    float* __restrict__ out,
                                    char* xs, int slot, int tid) {
  constexpr int COL0 = HALF ? 7 : 0;
  constexpr int NCOL = HALF ? 10 : 9;
  constexpr int JN   = HALF ? 9 : 8;
  constexpr int JB   = HALF ? 8 : 0;
  constexpr int NW   = HALF ? 5 : 3;
  constexpr int WB   = HALF ? 2 : 0;
  constexpr int W2   = NCOL - 8;            // last window: 1 or 2 cols

  const int w = tid >> 6, lane = tid & 63, l15 = lane & 15, l4 = lane >> 4;
  const int c = w * 16 + l15;

  bf16x8 bfr[2][4];
#pragma unroll
  for (int sel = 0; sel < 2; ++sel)
#pragma unroll
    for (int ks = 0; ks < 4; ++ks)
      bfr[sel][ks] = Wpack[(sel * 128 + c) * 16 + ks * 4 + l4];
  bf16x8 wtp[NW];
#pragma unroll
  for (int r = 0; r < NW; ++r)
    wtp[r] = *(const bf16x8*)(wt + c * 64 + (WB + r) * 8);

  f32x4 oa[JN];
#pragma unroll
  for (int j = 0; j < JN; ++j) oa[j] = (f32x4){0.f, 0.f, 0.f, 0.f};

  float4 v[4];   // prefetch regs — consumed by STAGE immediately each iter

  // Unconditional clamped loads => static vmcnt counting stays exact.
#define LOADSEG(T, CB, NCS, NL) do {                                      \
    const float* xp_ = x + (size_t)(T) * (FPT * XROW) + (CB) * FD;        \
    _Pragma("unroll")                                                     \
    for (int i_ = 0; i_ < (NL); ++i_) {                                   \
      int g_ = tid + i_ * 512;                                            \
      if (g_ > (NCS) * 256 - 1) g_ = (NCS) * 256 - 1;                     \
      const int fr_ = g_ / ((NCS) * 16), rem_ = g_ - fr_ * ((NCS) * 16);  \
      const float* sp_ = xp_ + (size_t)fr_ * XROW + rem_ * 8;             \
      v[2 * i_]     = *(const float4*)sp_;                                \
      v[2 * i_ + 1] = *(const float4*)(sp_ + 4);                          \
    }                                                                     \
  } while (0)

#define STAGESEG(SB, NCS, NL) do {                                        \
    _Pragma("unroll")                                                     \
    for (int i_ = 0; i_ < (NL); ++i_) {                                   \
      const int g_ = tid + i_ * 512;                                      \
      if (((NCS) * 256) % 512 == 0 || g_ < (NCS) * 256) {                 \
        const int fr_ = g_ / ((NCS) * 16);                                \
        const int byte_ = (g_ * 16) ^ ((fr_ & 7) << 4);                   \
        *(bf16x8*)((char*)(SB) + byte_) = pack8(v[2 * i_], v[2 * i_ + 1]); \
      }                                                                   \
    }                                                                     \
  } while (0)

#define STORES(T) do {                                                    \
    float* ob_ = out + (size_t)(T) * (FPT * XROW);                        \
    _Pragma("unroll")                                                     \
    for (int j_ = 0; j_ < JN; ++j_) {                                     \
      _Pragma("unroll")                                                   \
      for (int q_ = 0; q_ < 4; ++q_)                                      \
        ob_[(size_t)(l4 * 4 + q_) * XROW + (JB + j_) * FD + c] = oa[j_][q_]; \
      oa[j_] = (f32x4){0.f, 0.f, 0.f, 0.f};                               \
    }                                                                     \
  } while (0)

  char* s0 = xs;
  char* s1 = xs + SLOT;
  const int t0 = slot * TPB;

  LOADSEG(t0, COL0, 4, 2);
  // s=0
  STAGESEG(s0, 4, 2);  LOADSEG(t0, COL0 + 4, 4, 2);  BARR();
  cwin<HALF, 0, 4, NW>(s0, l15, l4, bfr, wtp, oa);
  // s=1
  STAGESEG(s1, 4, 2);  LOADSEG(t0, COL0 + 8, W2, 1); BARR();
  cwin<HALF, 4, 8, NW>(s1, l15, l4, bfr, wtp, oa);
  // s=2  (loads for next tile issued BEFORE the stores -> counted wait)
  STAGESEG(s0, W2, 1); LOADSEG(t0 + 1, COL0, 4, 2);  BARR();
  cwin<HALF, 8, NCOL, NW>(s0, l15, l4, bfr, wtp, oa);
  STORES(t0);
  // s=3
  STAGESEG(s1, 4, 2);  LOADSEG(t0 + 1, COL0 + 4, 4, 2);  BARR();
  cwin<HALF, 0, 4, NW>(s1, l15, l4, bfr, wtp, oa);
  // s=4
  STAGESEG(s0, 4, 2);  LOADSEG(t0 + 1, COL0 + 8, W2, 1); BARR();
  cwin<HALF, 4, 8, NW>(s0, l15, l4, bfr, wtp, oa);
  // s=5
  STAGESEG(s1, W2, 1); BARR();
  cwin<HALF, 8, NCOL, NW>(s1, l15, l4, bfr, wtp, oa);
  STORES(t0 + 1);

#undef LOADSEG
#undef STAGESEG
#undef STORES
}

// ---------------------------------------------------------------------------
__global__ __launch_bounds__(512, 4) void fused_kernel(
    const float*  __restrict__ x,
    const bf16x8* __restrict__ Wpack,
    const ushort* __restrict__ wt,
    float*        __restrict__ out) {
  __shared__ __align__(16) char xs[2 * SLOT];   // 32 KB
  const int slot = blockIdx.x >> 1;
  if (blockIdx.x & 1) run<1>(x, Wpack, wt, out, xs, slot, threadIdx.x);
  else                run<0>(x, Wpack, wt, out, xs, slot, threadIdx.x);
}

// ---------------------------------------------------------------------------
extern "C" void kernel_launch(void* const* d_in, const int* in_sizes, int n_in,
                              void* d_out, int out_size, void* d_ws, size_t ws_size,
                              hipStream_t stream) {
  const float* x = (const float*)d_in[0];   // [B,T,J,F]
  const float* W = (const float*)d_in[1];   // [2,F,C]
  const float* e = (const float*)d_in[2];   // [C,NNZ]
  float* out = (float*)d_out;

  bf16x8* Wpack = (bf16x8*)d_ws;
  ushort* wt    = (ushort*)((char*)d_ws + WS_WT);

  prep_pack_kernel<<<17, 256, 0, stream>>>(W, e, Wpack, wt);

  const int frames = in_sizes[0] / XROW;    // 15552
  const int ntiles = frames / FPT;          // 972
  const int blocks = (ntiles / TPB) * 2;    // 972
  fused_kernel<<<blocks, 512, 0, stream>>>(x, Wpack, wt, out);
}

// Round 11
// 125.242 us; speedup vs baseline: 1.7810x; 1.1525x over previous
//
#include <hip/hip_runtime.h>

#define NJ   17
#define FD   128
#define NC   128
#define NNZ  49
#define FPT  16                 // frames per tile (= MFMA M)
#define XROW (NJ*FD)            // 2176 floats per frame
#define TPB  2                  // tiles per block
#define SLOT 32768              // LDS slot bytes (4-col f32 window)
#define WS_WT 65536             // ws offset of wt[128][64] bf16

typedef __attribute__((ext_vector_type(8))) short bf16x8;
typedef __attribute__((ext_vector_type(4))) float f32x4;

__device__ __forceinline__ ushort f2bf(float f) {   // f32 -> bf16 RNE
  unsigned u = __float_as_uint(f);
  u = (u + 0x7fffu + ((u >> 16) & 1u)) >> 16;
  return (ushort)u;
}
__device__ __forceinline__ float bf2f(ushort s) {
  return __uint_as_float(((unsigned)s) << 16);
}
__device__ __forceinline__ unsigned cvtpk(float a, float b) {
  unsigned r;
  asm("v_cvt_pk_bf16_f32 %0, %1, %2" : "=v"(r) : "v"(a), "v"(b));
  return r;
}
__device__ __forceinline__ bf16x8 pack8(f32x4 a, f32x4 b) {
  union { unsigned u[4]; bf16x8 v; } r;
  r.u[0] = cvtpk(a[0], a[1]); r.u[1] = cvtpk(a[2], a[3]);
  r.u[2] = cvtpk(b[0], b[1]); r.u[3] = cvtpk(b[2], b[3]);
  return r.v;
}
__device__ __forceinline__ void axpy(f32x4& o, float s, f32x4 h) {
  o[0] += s * h[0]; o[1] += s * h[1]; o[2] += s * h[2]; o[3] += s * h[3];
}

// counted-vmcnt wait: loads stay in flight, wait only for what's needed
#define WVM(N) do { asm volatile("s_waitcnt vmcnt(" #N ")" ::: "memory"); \
                    __builtin_amdgcn_sched_barrier(0); } while (0)
// LDS-only barrier: drains ds ops (lgkm), leaves vmem in flight
#define BARR() do { asm volatile("s_waitcnt lgkmcnt(0)" ::: "memory"); \
                    __builtin_amdgcn_s_barrier(); \
                    __builtin_amdgcn_sched_barrier(0); } while (0)

// ---------------------------------------------------------------------------
// Compile-time Human3.6M skeleton tables (validated end-to-end r6-r10).
// ---------------------------------------------------------------------------
struct CI { int col, dk, n, jl[3], kk[3]; };
constexpr CI TAB0[9] = {          // half 0: out joints 0..7, cols 0..8
  {0,  0, 3, {1,4,7}, {4,12,20}},
  {1,  5, 2, {0,2,0}, {1,7,0}},
  {2,  8, 2, {1,3,0}, {6,10,0}},
  {3, 11, 1, {2,0,0}, {9,0,0}},
  {4, 13, 2, {0,5,0}, {2,15,0}},
  {5, 16, 2, {4,6,0}, {14,18,0}},
  {6, 19, 1, {5,0,0}, {17,0,0}},
  {7, 21, 1, {0,0,0}, {3,0,0}},
  {8, -1, 1, {7,0,0}, {22,0,0}},
};
constexpr CI TAB1[10] = {         // half 1: out joints 8..16 (local j-8), cols 7..16
  {7, -1, 1, {0,0,0}, {23,0,0}},
  {8, 24, 3, {1,3,6}, {28,33,41}},
  {9, 29, 2, {0,2,0}, {25,31,0}},
  {10,32, 1, {1,0,0}, {30,0,0}},
  {11,34, 2, {0,4,0}, {26,36,0}},
  {12,37, 2, {3,5,0}, {35,39,0}},
  {13,40, 1, {4,0,0}, {38,0,0}},
  {14,42, 2, {0,7,0}, {27,44,0}},
  {15,45, 2, {6,8,0}, {43,47,0}},
  {16,48, 1, {7,0,0}, {46,0,0}},
};
constexpr int RP[NJ + 1] = {0,4,7,10,12,15,18,20,23,28,31,33,36,39,41,44,47,49};

// ---------------------------------------------------------------------------
// Prep (17 blocks x 256) — unchanged (validated r6-r10).
// ---------------------------------------------------------------------------
__global__ void prep_pack_kernel(const float* __restrict__ W,
                                 const float* __restrict__ e,
                                 bf16x8* __restrict__ Wpack,
                                 ushort* __restrict__ wt) {
  const int tid = threadIdx.x;
  if (blockIdx.x < 16) {
    const int idx = blockIdx.x * 256 + tid, n = idx >> 4, kb = idx & 15;
    const float* Wp = W + (size_t)(n >> 7) * (FD * NC) + (n & 127);
    bf16x8 v;
#pragma unroll
    for (int q = 0; q < 8; ++q) v[q] = (short)f2bf(Wp[(size_t)(kb * 8 + q) * NC]);
    Wpack[idx] = v;
  } else if (tid < NC) {
    const int c = tid;
    for (int j = 0; j < NJ; ++j) {
      const int k0 = RP[j], k1 = RP[j + 1];
      float m = -1e30f;
      for (int k = k0; k < k1; ++k) m = fmaxf(m, e[c * NNZ + k]);
      float s = 0.f;
      for (int k = k0; k < k1; ++k) s += expf(e[c * NNZ + k] - m);
      const float inv = 1.f / s;
      for (int k = k0; k < k1; ++k) wt[c * 64 + k] = f2bf(expf(e[c * NNZ + k] - m) * inv);
    }
    for (int k = NNZ; k < 64; ++k) wt[c * 64 + k] = 0;
  }
}

// ---------------------------------------------------------------------------
// Compute one col-window [CI_LO, CI_HI) from an f32 LDS slot.
// LDS layout: off(f,lc,e8,h) = ((lc*16+e8)*16+f)*32 + h*16, XOR key (f&4)<<2
// (key is baked into the staged global source -> 2-way conflicts only).
// af = elements k = ks*32 + l4*8 + 0..7 of (frame=l15, col) — r7 mapping.
// ---------------------------------------------------------------------------
template <int HALF, int CI_LO, int CI_HI, int NW>
__device__ __forceinline__ void cwin(const char* sb, int l15, int l4,
                                     const bf16x8 (&bfr)[2][4],
                                     const bf16x8 (&wtp)[NW],
                                     f32x4* oa) {
  constexpr int JB = HALF ? 8 : 0;
  constexpr int WB = HALF ? 2 : 0;
  const CI* TT = HALF ? TAB1 : TAB0;
  const int key = (l15 & 4) << 2;
#pragma unroll
  for (int ci = CI_LO; ci < CI_HI; ++ci) {
    const int lc = ci - CI_LO, dk = TT[ci].dk, nn = TT[ci].n;
    bf16x8 af[4];
#pragma unroll
    for (int ks = 0; ks < 4; ++ks) {
      const int base = ((lc * 16 + ks * 4 + l4) * 16 + l15) * 32;
      const f32x4 lo = *(const f32x4*)(sb + (base ^ key));
      const f32x4 hi = *(const f32x4*)(sb + ((base + 16) ^ key));
      af[ks] = pack8(lo, hi);
    }
    f32x4 h1 = (f32x4){0.f, 0.f, 0.f, 0.f};
#pragma unroll
    for (int ks = 0; ks < 4; ++ks)
      h1 = __builtin_amdgcn_mfma_f32_16x16x32_bf16(af[ks], bfr[1][ks], h1, 0, 0, 0);
    if (dk >= 0) {
      f32x4 h0 = (f32x4){0.f, 0.f, 0.f, 0.f};
#pragma unroll
      for (int ks = 0; ks < 4; ++ks)
        h0 = __builtin_amdgcn_mfma_f32_16x16x32_bf16(af[ks], bfr[0][ks], h0, 0, 0, 0);
      axpy(oa[TT[ci].col - JB], bf2f((ushort)wtp[(dk >> 3) - WB][dk & 7]), h0);
    }
#pragma unroll
    for (int o = 0; o < 3; ++o)
      if (o < nn)
        axpy(oa[TT[ci].jl[o]],
             bf2f((ushort)wtp[(TT[ci].kk[o] >> 3) - WB][TT[ci].kk[o] & 7]), h1);
  }
}

// ---------------------------------------------------------------------------
// Per-half driver: 2 tiles x 3 col-windows, global_load_lds staging (zero
// VGPR -> no spill), 2-slot ping-pong, counted vmcnt, lgkm-only barriers.
// ---------------------------------------------------------------------------
template <int HALF>
__device__ __forceinline__ void run(const float* __restrict__ x,
                                    const bf16x8* __restrict__ Wpack,
                                    const ushort* __restrict__ wt,
                                    float* __restrict__ out,
                                    char* xs, int slot, int tid) {
  constexpr int COL0 = HALF ? 7 : 0;
  constexpr int NCOL = HALF ? 10 : 9;
  constexpr int JN   = HALF ? 9 : 8;
  constexpr int JB   = HALF ? 8 : 0;
  constexpr int NW   = HALF ? 5 : 3;
  constexpr int WB   = HALF ? 2 : 0;
  constexpr int W2   = NCOL - 8;            // last window: 1 (h0) or 2 (h1) cols

  const int w = tid >> 6, lane = tid & 63, l15 = lane & 15, l4 = lane >> 4;
  const int c = w * 16 + l15;

  bf16x8 bfr[2][4];
#pragma unroll
  for (int sel = 0; sel < 2; ++sel)
#pragma unroll
    for (int ks = 0; ks < 4; ++ks)
      bfr[sel][ks] = Wpack[(sel * 128 + c) * 16 + ks * 4 + l4];
  bf16x8 wtp[NW];
#pragma unroll
  for (int r = 0; r < NW; ++r)
    wtp[r] = *(const bf16x8*)(wt + c * 64 + (WB + r) * 8);

  f32x4 oa[JN];
#pragma unroll
  for (int j = 0; j < JN; ++j) oa[j] = (f32x4){0.f, 0.f, 0.f, 0.f};

  // zero-register staging: one col (8192 B) per round, LDS dest linear
  // (wave base + lane*16), swizzle pre-baked into the per-lane global source
  // (h ^= (f>>2)&1  <=>  read-side addr ^ ((l15&4)<<2) — involution pair).
#define ISSUE(T, CB, NCS, SB) do {                                          \
    _Pragma("unroll")                                                       \
    for (int i_ = 0; i_ < (NCS); ++i_) {                                    \
      const int o16_ = i_ * 512 + tid;                                      \
      const int e8_ = (o16_ >> 5) & 15, f_ = (o16_ >> 1) & 15;              \
      const int h_ = (o16_ & 1) ^ ((f_ >> 2) & 1);                          \
      const float* src_ = x + ((size_t)(T) * FPT + f_) * XROW +             \
                          ((CB) + i_) * FD + e8_ * 8 + h_ * 4;              \
      __builtin_amdgcn_global_load_lds(src_,                                \
          (void*)((SB) + i_ * 8192 + w * 1024), 16, 0, 0);                  \
    }                                                                       \
  } while (0)

#define STORES(T) do {                                                      \
    float* ob_ = out + (size_t)(T) * (FPT * XROW);                          \
    _Pragma("unroll")                                                       \
    for (int j_ = 0; j_ < JN; ++j_) {                                       \
      _Pragma("unroll")                                                     \
      for (int q_ = 0; q_ < 4; ++q_)                                        \
        ob_[(size_t)(l4 * 4 + q_) * XROW + (JB + j_) * FD + c] = oa[j_][q_]; \
      oa[j_] = (f32x4){0.f, 0.f, 0.f, 0.f};                                 \
    }                                                                       \
  } while (0)

  char* s0 = xs;
  char* s1 = xs + SLOT;
  const int t0 = slot * TPB;

  ISSUE(t0, COL0, 4, s0);                 // window A0 -> slot0
  ISSUE(t0, COL0 + 4, 4, s1);             // window B0 -> slot1
  WVM(4); BARR();                         // A0 landed (B0 in flight)

  cwin<HALF, 0, 4, NW>(s0, l15, l4, bfr, wtp, oa);
  BARR(); ISSUE(t0, COL0 + 8, W2, s0);    // C0 -> slot0 (A0 fully read)
  if constexpr (W2 == 1) WVM(1); else WVM(2);   // B0 landed
  BARR();
  cwin<HALF, 4, 8, NW>(s1, l15, l4, bfr, wtp, oa);
  BARR(); ISSUE(t0 + 1, COL0, 4, s1);     // A1 -> slot1
  WVM(4); BARR();                         // C0 landed (A1 in flight)
  cwin<HALF, 8, NCOL, NW>(s0, l15, l4, bfr, wtp, oa);
  STORES(t0);                             // JN*4 stores enter vmcnt FIFO
  BARR(); ISSUE(t0 + 1, COL0 + 4, 4, s0); // B1 -> slot0
  if constexpr (HALF) WVM(40); else WVM(36);    // A1 landed (stores+B1 = S+4)
  BARR();
  cwin<HALF, 0, 4, NW>(s1, l15, l4, bfr, wtp, oa);
  BARR(); ISSUE(t0 + 1, COL0 + 8, W2, s1);  // C1 -> slot1
  if constexpr (W2 == 1) WVM(1); else WVM(2);   // B1 landed
  BARR();
  cwin<HALF, 4, 8, NW>(s0, l15, l4, bfr, wtp, oa);
  BARR(); WVM(0); BARR();                 // C1 landed (epilogue drain)
  cwin<HALF, 8, NCOL, NW>(s1, l15, l4, bfr, wtp, oa);
  STORES(t0 + 1);

#undef ISSUE
#undef STORES
}

// ---------------------------------------------------------------------------
__global__ __launch_bounds__(512, 4) void fused_kernel(
    const float*  __restrict__ x,
    const bf16x8* __restrict__ Wpack,
    const ushort* __restrict__ wt,
    float*        __restrict__ out) {
  __shared__ __align__(16) char xs[2 * SLOT];   // 64 KB -> 2 blocks/CU
  const int slot = blockIdx.x >> 1;
  if (blockIdx.x & 1) run<1>(x, Wpack, wt, out, xs, slot, threadIdx.x);
  else                run<0>(x, Wpack, wt, out, xs, slot, threadIdx.x);
}

// ---------------------------------------------------------------------------
extern "C" void kernel_launch(void* const* d_in, const int* in_sizes, int n_in,
                              void* d_out, int out_size, void* d_ws, size_t ws_size,
                              hipStream_t stream) {
  const float* x = (const float*)d_in[0];   // [B,T,J,F]
  const float* W = (const float*)d_in[1];   // [2,F,C]
  const float* e = (const float*)d_in[2];   // [C,NNZ]
  float* out = (float*)d_out;

  bf16x8* Wpack = (bf16x8*)d_ws;
  ushort* wt    = (ushort*)((char*)d_ws + WS_WT);

  prep_pack_kernel<<<17, 256, 0, stream>>>(W, e, Wpack, wt);

  const int frames = in_sizes[0] / XROW;    // 15552
  const int ntiles = frames / FPT;          // 972
  const int blocks = (ntiles / TPB) * 2;    // 972
  fused_kernel<<<blocks, 512, 0, stream>>>(x, Wpack, wt, out);
}

// Round 12
// 107.372 us; speedup vs baseline: 2.0775x; 1.1664x over previous
//
#include <hip/hip_runtime.h>

#define NJ   17
#define FD   128
#define NC   128
#define NNZ  49
#define FPT  16                 // frames per tile (= MFMA M)
#define XROW (NJ*FD)            // 2176 floats per frame
#define WS_WT 65536             // ws offset of wt[128][64] bf16

typedef __attribute__((ext_vector_type(8))) short bf16x8;
typedef __attribute__((ext_vector_type(4))) float f32x4;

__device__ __forceinline__ ushort f2bf(float f) {   // f32 -> bf16 RNE
  unsigned u = __float_as_uint(f);
  u = (u + 0x7fffu + ((u >> 16) & 1u)) >> 16;
  return (ushort)u;
}
__device__ __forceinline__ float bf2f(ushort s) {
  return __uint_as_float(((unsigned)s) << 16);
}
__device__ __forceinline__ unsigned cvtpk(float a, float b) {
  unsigned r;
  asm("v_cvt_pk_bf16_f32 %0, %1, %2" : "=v"(r) : "v"(a), "v"(b));
  return r;
}
__device__ __forceinline__ bf16x8 pack8(float4 a, float4 b) {
  union { unsigned u[4]; bf16x8 v; } r;
  r.u[0] = cvtpk(a.x, a.y); r.u[1] = cvtpk(a.z, a.w);
  r.u[2] = cvtpk(b.x, b.y); r.u[3] = cvtpk(b.z, b.w);
  return r.v;
}
__device__ __forceinline__ void axpy(f32x4& o, float s, f32x4 h) {
  o[0] += s * h[0]; o[1] += s * h[1]; o[2] += s * h[2]; o[3] += s * h[3];
}

// ---------------------------------------------------------------------------
// Compile-time Human3.6M skeleton tables (validated end-to-end r6-r11).
// ---------------------------------------------------------------------------
struct CI { int col, dk, n, jl[3], kk[3]; };
constexpr CI TAB0[9] = {          // half 0: out joints 0..7, cols 0..8
  {0,  0, 3, {1,4,7}, {4,12,20}},
  {1,  5, 2, {0,2,0}, {1,7,0}},
  {2,  8, 2, {1,3,0}, {6,10,0}},
  {3, 11, 1, {2,0,0}, {9,0,0}},
  {4, 13, 2, {0,5,0}, {2,15,0}},
  {5, 16, 2, {4,6,0}, {14,18,0}},
  {6, 19, 1, {5,0,0}, {17,0,0}},
  {7, 21, 1, {0,0,0}, {3,0,0}},
  {8, -1, 1, {7,0,0}, {22,0,0}},
};
constexpr CI TAB1[10] = {         // half 1: out joints 8..16 (local j-8), cols 7..16
  {7, -1, 1, {0,0,0}, {23,0,0}},
  {8, 24, 3, {1,3,6}, {28,33,41}},
  {9, 29, 2, {0,2,0}, {25,31,0}},
  {10,32, 1, {1,0,0}, {30,0,0}},
  {11,34, 2, {0,4,0}, {26,36,0}},
  {12,37, 2, {3,5,0}, {35,39,0}},
  {13,40, 1, {4,0,0}, {38,0,0}},
  {14,42, 2, {0,7,0}, {27,44,0}},
  {15,45, 2, {6,8,0}, {43,47,0}},
  {16,48, 1, {7,0,0}, {46,0,0}},
};
constexpr int RP[NJ + 1] = {0,4,7,10,12,15,18,20,23,28,31,33,36,39,41,44,47,49};

// Early-flush schedule: local out-joints completed after each col (max 2).
// Derived from TAB contributor sets; -1 = none. Max live acc = 6 (half0)/5.
constexpr int FL0[9][2]  = {{-1,-1},{-1,-1},{1,-1},{2,3},{-1,-1},
                            {4,-1},{5,6},{0,-1},{7,-1}};
constexpr int FL1[10][2] = {{-1,-1},{-1,-1},{-1,-1},{1,2},{-1,-1},
                            {3,-1},{4,5},{0,-1},{6,-1},{7,8}};

// ---------------------------------------------------------------------------
// Prep (17 blocks x 256) — unchanged (validated r6-r11).
// ---------------------------------------------------------------------------
__global__ void prep_pack_kernel(const float* __restrict__ W,
                                 const float* __restrict__ e,
                                 bf16x8* __restrict__ Wpack,
                                 ushort* __restrict__ wt) {
  const int tid = threadIdx.x;
  if (blockIdx.x < 16) {
    const int idx = blockIdx.x * 256 + tid, n = idx >> 4, kb = idx & 15;
    const float* Wp = W + (size_t)(n >> 7) * (FD * NC) + (n & 127);
    bf16x8 v;
#pragma unroll
    for (int q = 0; q < 8; ++q) v[q] = (short)f2bf(Wp[(size_t)(kb * 8 + q) * NC]);
    Wpack[idx] = v;
  } else if (tid < NC) {
    const int c = tid;
    for (int j = 0; j < NJ; ++j) {
      const int k0 = RP[j], k1 = RP[j + 1];
      float m = -1e30f;
      for (int k = k0; k < k1; ++k) m = fmaxf(m, e[c * NNZ + k]);
      float s = 0.f;
      for (int k = k0; k < k1; ++k) s += expf(e[c * NNZ + k] - m);
      const float inv = 1.f / s;
      for (int k = k0; k < k1; ++k) wt[c * 64 + k] = f2bf(expf(e[c * NNZ + k] - m) * inv);
    }
    for (int k = NNZ; k < 64; ++k) wt[c * 64 + k] = 0;
  }
}

// ---------------------------------------------------------------------------
// One block = (tile, half, 64-channel group), 256 thr = 4 waves.
// Stage bf16 x-slice to LDS (r7-validated swizzle), ONE barrier, then per col:
// ds_read A-frags -> MFMA h1(+h0) -> in-register axpy -> EARLY FLUSH stores.
// ---------------------------------------------------------------------------
template <int HALF>
__device__ __forceinline__ void run(const float* __restrict__ x,
                                    const bf16x8* __restrict__ Wpack,
                                    const ushort* __restrict__ wt,
                                    float* __restrict__ out,
                                    short* xs, int tile, int cg, int tid) {
  constexpr int COL0 = HALF ? 7 : 0;
  constexpr int NCOL = HALF ? 10 : 9;
  constexpr int JN   = HALF ? 9 : 8;
  constexpr int JB   = HALF ? 8 : 0;
  constexpr int NW   = HALF ? 5 : 3;
  constexpr int WB   = HALF ? 2 : 0;
  const CI* TT = HALF ? TAB1 : TAB0;
  const int (*FL)[2] = HALF ? FL1 : FL0;

  const int w = tid >> 6, lane = tid & 63, l15 = lane & 15, l4 = lane >> 4;
  const int c = cg * 64 + w * 16 + l15;

  // persistent B frags + softmax-weight rows (candidates for AGPR)
  bf16x8 bfr[2][4];
#pragma unroll
  for (int sel = 0; sel < 2; ++sel)
#pragma unroll
    for (int ks = 0; ks < 4; ++ks)
      bfr[sel][ks] = Wpack[(sel * 128 + c) * 16 + ks * 4 + l4];
  bf16x8 wtp[NW];
#pragma unroll
  for (int r = 0; r < NW; ++r)
    wtp[r] = *(const bf16x8*)(wt + c * 64 + (WB + r) * 8);

  const float* xt = x + (size_t)tile * (FPT * XROW) + COL0 * FD;
  float4 v[12];   // 6 float4-pairs max in flight; all die into STWP quickly

#define LOADP(I, S) do {                                                  \
    const int g_ = tid + (I) * 256;                                       \
    const int fr_ = g_ / (NCOL * 16), rem_ = g_ - fr_ * (NCOL * 16);      \
    const float* sp_ = xt + (size_t)fr_ * XROW + rem_ * 8;                \
    v[(S)] = *(const float4*)sp_; v[(S) + 1] = *(const float4*)(sp_ + 4); \
  } while (0)
#define STWP(I, S) do {                                                   \
    const int g_ = tid + (I) * 256;                                       \
    const int fr_ = g_ / (NCOL * 16);                                     \
    const int byte_ = (g_ * 16) ^ ((fr_ & 7) << 4);                       \
    *(bf16x8*)((char*)xs + byte_) = pack8(v[(S)], v[(S) + 1]);            \
  } while (0)

  // staging: NPAIR = 9 (half0) / 10 (half1) pairs, 3-pair bursts, 6 deep
  LOADP(0, 0); LOADP(1, 2); LOADP(2, 4);
  LOADP(3, 6); LOADP(4, 8); LOADP(5, 10);
  STWP(0, 0); STWP(1, 2); STWP(2, 4);
  LOADP(6, 0); LOADP(7, 2); LOADP(8, 4);
  STWP(3, 6); STWP(4, 8); STWP(5, 10);
  if (HALF) LOADP(9, 6);
  STWP(6, 0); STWP(7, 2); STWP(8, 4);
  if (HALF) STWP(9, 6);
  __syncthreads();                       // the only barrier in the kernel

  f32x4 oa[JN];
#pragma unroll
  for (int j = 0; j < JN; ++j) oa[j] = (f32x4){0.f, 0.f, 0.f, 0.f};

  float* const ob = out + (size_t)tile * (FPT * XROW);

#pragma unroll
  for (int ci = 0; ci < NCOL; ++ci) {
    const int dk = TT[ci].dk, nn = TT[ci].n;
    bf16x8 af[4];
#pragma unroll
    for (int ks = 0; ks < 4; ++ks) {
      const int byte = l15 * (NCOL * 256) + ci * 256 +
                       (((ks * 4 + l4) * 16) ^ ((l15 & 7) << 4));
      af[ks] = *(const bf16x8*)((const char*)xs + byte);
    }
    f32x4 h1 = (f32x4){0.f, 0.f, 0.f, 0.f};
#pragma unroll
    for (int ks = 0; ks < 4; ++ks)
      h1 = __builtin_amdgcn_mfma_f32_16x16x32_bf16(af[ks], bfr[1][ks], h1, 0, 0, 0);
    if (dk >= 0) {                       // diagonal term (W0 product)
      f32x4 h0 = (f32x4){0.f, 0.f, 0.f, 0.f};
#pragma unroll
      for (int ks = 0; ks < 4; ++ks)
        h0 = __builtin_amdgcn_mfma_f32_16x16x32_bf16(af[ks], bfr[0][ks], h0, 0, 0, 0);
      axpy(oa[TT[ci].col - JB], bf2f((ushort)wtp[(dk >> 3) - WB][dk & 7]), h0);
    }
#pragma unroll
    for (int o = 0; o < 3; ++o)
      if (o < nn)
        axpy(oa[TT[ci].jl[o]],
             bf2f((ushort)wtp[(TT[ci].kk[o] >> 3) - WB][TT[ci].kk[o] & 7]), h1);

    // early flush: completed joints stored now (spreads stores, frees regs)
#pragma unroll
    for (int fi = 0; fi < 2; ++fi) {
      const int fj = FL[ci][fi];
      if (fj >= 0) {
#pragma unroll
        for (int q = 0; q < 4; ++q)
          ob[(size_t)(l4 * 4 + q) * XROW + (JB + fj) * FD + c] = oa[fj][q];
      }
    }
  }
#undef LOADP
#undef STWP
}

// ---------------------------------------------------------------------------
__global__ __launch_bounds__(256, 4) void fused_kernel(
    const float*  __restrict__ x,
    const bf16x8* __restrict__ Wpack,
    const ushort* __restrict__ wt,
    float*        __restrict__ out) {
  __shared__ __align__(16) short xs[FPT * 10 * FD];   // 40960 B -> 4 blocks/CU
  const int tile = blockIdx.x >> 2;
  const int half = (blockIdx.x >> 1) & 1;
  const int cg   = blockIdx.x & 1;
  if (half) run<1>(x, Wpack, wt, out, xs, tile, cg, threadIdx.x);
  else      run<0>(x, Wpack, wt, out, xs, tile, cg, threadIdx.x);
}

// ---------------------------------------------------------------------------
extern "C" void kernel_launch(void* const* d_in, const int* in_sizes, int n_in,
                              void* d_out, int out_size, void* d_ws, size_t ws_size,
                              hipStream_t stream) {
  const float* x = (const float*)d_in[0];   // [B,T,J,F]
  const float* W = (const float*)d_in[1];   // [2,F,C]
  const float* e = (const float*)d_in[2];   // [C,NNZ]
  float* out = (float*)d_out;

  bf16x8* Wpack = (bf16x8*)d_ws;
  ushort* wt    = (ushort*)((char*)d_ws + WS_WT);

  prep_pack_kernel<<<17, 256, 0, stream>>>(W, e, Wpack, wt);

  const int frames = in_sizes[0] / XROW;    // 15552
  const int ntiles = frames / FPT;          // 972
  fused_kernel<<<ntiles * 4, 256, 0, stream>>>(x, Wpack, wt, out);
}